// Round 1
// baseline (41.628 us; speedup 1.0000x reference)
//
#include <hip/hip_runtime.h>

#define B_N   2048
#define K_N   8
#define L_N   256
#define KLTOT (K_N * L_N)       // 2048
#define H1N   18
#define H2N   12
#define EPSV  1e-8f

#define NCHUNK     32
#define CHUNK_ROWS (B_N / NCHUNK)   // 64

#define KLT  16                 // kl columns per block
#define RPT  8                  // batch rows per thread
#define GRP  16                 // thread groups (tid>>4)
#define ROWS (RPT * GRP)        // 128 batch rows per block

// ---------------- stats: partial sums over batch chunks ----------------
__global__ __launch_bounds__(256) void stats_partial(const float* __restrict__ x,
                                                     float* __restrict__ part) {
    int kl = blockIdx.x * 256 + threadIdx.x;
    int chunk = blockIdx.y;
    const float* p = x + (size_t)(chunk * CHUNK_ROWS) * KLTOT + kl;
    float s = 0.f, s2 = 0.f;
#pragma unroll 8
    for (int r = 0; r < CHUNK_ROWS; ++r) {
        float v = p[(size_t)r * KLTOT];
        s += v;
        s2 += v * v;
    }
    part[(chunk * KLTOT + kl) * 2 + 0] = s;
    part[(chunk * KLTOT + kl) * 2 + 1] = s2;
}

__global__ __launch_bounds__(256) void stats_finalize(const float* __restrict__ part,
                                                      float* __restrict__ mu_out,
                                                      float* __restrict__ rstd_out) {
    int kl = blockIdx.x * 256 + threadIdx.x;
    float s = 0.f, s2 = 0.f;
#pragma unroll 8
    for (int c = 0; c < NCHUNK; ++c) {
        s  += part[(c * KLTOT + kl) * 2 + 0];
        s2 += part[(c * KLTOT + kl) * 2 + 1];
    }
    float mu  = s / (float)B_N;
    float var = fmaxf(s2 / (float)B_N - mu * mu, 0.f);
    float sd  = sqrtf(var);
    mu_out[kl]   = mu;
    rstd_out[kl] = 1.f / (sd + EPSV);
}

// ---------------- main fused MLP kernel ----------------
__device__ __forceinline__ void fma4(float4& a, float s, const float4& w) {
    a.x = fmaf(s, w.x, a.x);
    a.y = fmaf(s, w.y, a.y);
    a.z = fmaf(s, w.z, a.z);
    a.w = fmaf(s, w.w, a.w);
}

__global__ __launch_bounds__(256) void mlp_main(
    const float* __restrict__ x,
    const float* __restrict__ W1, const float* __restrict__ b1,
    const float* __restrict__ W2, const float* __restrict__ b2,
    const float* __restrict__ W3, const float* __restrict__ b3,
    const float* __restrict__ muA, const float* __restrict__ rstdA,
    float* __restrict__ out)
{
    // LDS staging for KLT=16 columns
    __shared__ float lW1[KLT * H1N];          // kl-major, stride 18 -> 16 distinct banks
    __shared__ float lb1[KLT * H1N];
    __shared__ float lW2[H1N][KLT * H2N];     // [h][c*12+j] -> lane stride 12 dwords (2-way, free)
    __shared__ float lb2[KLT * H2N];
    __shared__ float lW3[KLT * H2N];
    __shared__ float lb3[KLT], lmu[KLT], lrstd[KLT];

    const int tid = threadIdx.x;
    const int kl0 = blockIdx.x * KLT;
    const int b0  = blockIdx.y * ROWS;

    // ---- stage weights (all chunks are contiguous in global: kl tile is leading dim) ----
    {
        const float4* src = (const float4*)(W2 + (size_t)kl0 * (H1N * H2N));
        for (int t = tid; t < (KLT * H1N * H2N) / 4; t += 256) {   // 864 float4
            float4 v = src[t];
            int idx = t * 4;
            int c   = idx / (H1N * H2N);
            int rem = idx - c * (H1N * H2N);
            int h   = rem / H2N;
            int j   = rem - h * H2N;        // multiple of 4
            *(float4*)&lW2[h][c * H2N + j] = v;
        }
        const float4* s1  = (const float4*)(W1 + (size_t)kl0 * H1N);
        const float4* s1b = (const float4*)(b1 + (size_t)kl0 * H1N);
        for (int t = tid; t < (KLT * H1N) / 4; t += 256) {         // 72 float4
            ((float4*)lW1)[t] = s1[t];
            ((float4*)lb1)[t] = s1b[t];
        }
        const float4* s2 = (const float4*)(b2 + (size_t)kl0 * H2N);
        const float4* s3 = (const float4*)(W3 + (size_t)kl0 * H2N);
        for (int t = tid; t < (KLT * H2N) / 4; t += 256) {         // 48 float4
            ((float4*)lb2)[t] = s2[t];
            ((float4*)lW3)[t] = s3[t];
        }
        if (tid < KLT) {
            lb3[tid]   = b3[kl0 + tid];
            lmu[tid]   = muA[kl0 + tid];
            lrstd[tid] = rstdA[kl0 + tid];
        }
    }
    __syncthreads();

    const int c    = tid & (KLT - 1);
    const int g    = tid >> 4;
    const int brow = b0 + g * RPT;

    const float m  = lmu[c];
    const float rs = lrstd[c];

    float xs[RPT];
    const float* xp = x + (size_t)brow * KLTOT + kl0 + c;
#pragma unroll
    for (int r = 0; r < RPT; ++r)
        xs[r] = (xp[(size_t)r * KLTOT] - m) * rs;

    // accumulators initialized with b2
    float4 acc[RPT][3];
    {
        float4 bb2a = *(const float4*)&lb2[c * H2N + 0];
        float4 bb2b = *(const float4*)&lb2[c * H2N + 4];
        float4 bb2c = *(const float4*)&lb2[c * H2N + 8];
#pragma unroll
        for (int r = 0; r < RPT; ++r) {
            acc[r][0] = bb2a;
            acc[r][1] = bb2b;
            acc[r][2] = bb2c;
        }
    }

#pragma unroll
    for (int h = 0; h < H1N; ++h) {
        float  w1v = lW1[c * H1N + h];
        float  b1v = lb1[c * H1N + h];
        float4 w2a = *(const float4*)&lW2[h][c * H2N + 0];
        float4 w2b = *(const float4*)&lW2[h][c * H2N + 4];
        float4 w2c = *(const float4*)&lW2[h][c * H2N + 8];
#pragma unroll
        for (int r = 0; r < RPT; ++r) {
            float h1v = fmaxf(fmaf(xs[r], w1v, b1v), 0.f);
            fma4(acc[r][0], h1v, w2a);
            fma4(acc[r][1], h1v, w2b);
            fma4(acc[r][2], h1v, w2c);
        }
    }

    // epilogue: relu(acc) dot W3 + b3
    float4 w3a = *(const float4*)&lW3[c * H2N + 0];
    float4 w3b = *(const float4*)&lW3[c * H2N + 4];
    float4 w3c = *(const float4*)&lW3[c * H2N + 8];
    float  b3v = lb3[c];
    float* op = out + (size_t)brow * KLTOT + kl0 + c;
#pragma unroll
    for (int r = 0; r < RPT; ++r) {
        float o = b3v;
        o += fmaxf(acc[r][0].x, 0.f) * w3a.x;
        o += fmaxf(acc[r][0].y, 0.f) * w3a.y;
        o += fmaxf(acc[r][0].z, 0.f) * w3a.z;
        o += fmaxf(acc[r][0].w, 0.f) * w3a.w;
        o += fmaxf(acc[r][1].x, 0.f) * w3b.x;
        o += fmaxf(acc[r][1].y, 0.f) * w3b.y;
        o += fmaxf(acc[r][1].z, 0.f) * w3b.z;
        o += fmaxf(acc[r][1].w, 0.f) * w3b.w;
        o += fmaxf(acc[r][2].x, 0.f) * w3c.x;
        o += fmaxf(acc[r][2].y, 0.f) * w3c.y;
        o += fmaxf(acc[r][2].z, 0.f) * w3c.z;
        o += fmaxf(acc[r][2].w, 0.f) * w3c.w;
        op[(size_t)r * KLTOT] = o;
    }
}

extern "C" void kernel_launch(void* const* d_in, const int* in_sizes, int n_in,
                              void* d_out, int out_size, void* d_ws, size_t ws_size,
                              hipStream_t stream) {
    const float* x  = (const float*)d_in[0];
    const float* W1 = (const float*)d_in[1];
    const float* b1 = (const float*)d_in[2];
    const float* W2 = (const float*)d_in[3];
    const float* b2 = (const float*)d_in[4];
    const float* W3 = (const float*)d_in[5];
    const float* b3 = (const float*)d_in[6];
    float* out = (float*)d_out;

    float* part  = (float*)d_ws;                    // NCHUNK*KLTOT*2 floats = 512 KB
    float* muA   = part + (size_t)NCHUNK * KLTOT * 2;
    float* rstdA = muA + KLTOT;

    stats_partial <<<dim3(KLTOT / 256, NCHUNK), 256, 0, stream>>>(x, part);
    stats_finalize<<<dim3(KLTOT / 256),          256, 0, stream>>>(part, muA, rstdA);
    mlp_main      <<<dim3(KLTOT / KLT, B_N / ROWS), 256, 0, stream>>>(
        x, W1, b1, W2, b2, W3, b3, muA, rstdA, out);
}